// Round 10
// baseline (234.956 us; speedup 1.0000x reference)
//
#include <hip/hip_runtime.h>

// B=64, K=8, H=W=128 (HW=16384). float32 in/out.
// out[0] = loss scalar; out[1..] = pred_perm (B,K,H,W) flat.
//
// 2-dispatch pipeline (r9's fused/spin design fully reverted -- it regressed).
// r7/r8/r9 counters triangulated the cost wall: OccupancyPercent 18.6%, VALU 20%,
// HBM 9%, conflicts 0 => LATENCY-bound at 2-4 blocks/CU. Fix = max TLP:
//   cost_kernel : 2048 blocks (i,s4,b) x 256 thr = 8 blocks/CU x 4 waves =
//                 32 waves/CU (100% occupancy; r8's inner loop compiled to
//                 28 VGPR, __launch_bounds__(256,8) pins <=64). Each block:
//                 ONE pred row span + 8 aug row spans (9 streams, acc[8]).
//                 p === b (mod 64) keeps a batch's 32 blocks on one XCD
//                 (r8-verified aug reuse: FETCH=33MB). Verified reduce-scatter
//                 epilogue -> part[p][9].
//   permute_kernel: 512 blocks (b*8+jcol): C built by summing 4 span-partials,
//                 verified Held-Karp DP (redundant per block), verified float4
//                 permuted row copy; one block per batch atomicAdds loss.

#define BB 64
#define KK 8
#define HW 16384
#define EPSF 1e-15f

// ---------- compile-time mask table: all 255 nonzero 8-bit masks, level-ordered by popcount ----------
struct MaskTab {
    unsigned char masks[255];
    int off[9];
};

constexpr MaskTab make_tab() {
    MaskTab t{};
    int idx = 0;
    for (int p = 1; p <= 8; ++p) {
        t.off[p - 1] = idx;
        for (int m = 1; m < 256; ++m) {
            int c = 0;
            for (int b = 0; b < 8; ++b) c += (m >> b) & 1;
            if (c == p) t.masks[idx++] = (unsigned char)m;
        }
    }
    t.off[8] = idx;
    return t;
}

__constant__ MaskTab kTab = make_tab();

__device__ __forceinline__ float dot4(float4 t, float4 l) {
    return t.x * l.x + t.y * l.y + t.z * l.z + t.w * l.w;
}

__device__ __forceinline__ float4 log4(float4 a) {
    float4 r;
    r.x = __logf(a.x + EPSF); r.y = __logf(a.y + EPSF);
    r.z = __logf(a.z + EPSF); r.w = __logf(a.w + EPSF);
    return r;
}

// ---------- phase 1: i-split cost partials at FULL occupancy ----------
// Grid 2048: p = i*256 + s4*64 + b  (i: pred row 0..7, s4: x-span 0..3, b: batch).
// Thread t covers quads {s4*1024 + m*256 + t : m in 0..3} (span = 4096 floats).
// part[p*9 + j] = partial cross[i][j]; part[p*9 + 8] = partial ent[i].
__global__ __launch_bounds__(256, 8) void cost_kernel(const float* __restrict__ pred,
                                                      const float* __restrict__ aug,
                                                      float* __restrict__ part,   // [2048][9]
                                                      float* __restrict__ out)
{
    __shared__ float red[4][9];

    const int p    = blockIdx.x;
    const int i    = p >> 8;         // pred row index 0..7
    const int s4   = (p >> 6) & 3;   // x-span 0..3
    const int b    = p & 63;         // batch; p === b (mod 64) -> same-XCD cluster
    const int tid  = threadIdx.x;
    const int wave = tid >> 6;
    const int lane = tid & 63;

    if (p == 0 && tid == 0) out[0] = 0.f;   // loss accumulator init (pre-atomics)

    const float* prow  = pred + ((size_t)b * KK + i) * HW;
    const float* abase = aug  + (size_t)b * KK * HW;

    float acc[8];
#pragma unroll
    for (int j = 0; j < 8; ++j) acc[j] = 0.f;
    float eacc = 0.f;

#pragma unroll
    for (int m = 0; m < 4; ++m) {
        const int e = s4 * 4096 + (m * 256 + tid) * 4;   // float offset within the row

        const float4 pq = *(const float4*)(prow + e);
        const float4 la = log4(pq);

#pragma unroll
        for (int j = 0; j < 8; ++j) {
            const float4 a = *(const float4*)(abase + (size_t)j * HW + e);
            acc[j] += dot4(a, la);
            if (j == i) eacc += dot4(a, log4(a));   // block-uniform branch
        }
    }

    // --- 3-round reduce-scatter over acc[8] (r8-verified) ---
#pragma unroll
    for (int r = 0; r < 3; ++r) {
        const int d    = 1 << r;
        const int half = 4 >> r;
        const bool hi  = (lane & d) != 0;
#pragma unroll
        for (int k = 0; k < half; ++k) {
            const float send = hi ? acc[k] : acc[k + half];
            const float recv = __shfl_xor(send, d);
            acc[k] = (hi ? acc[k + half] : acc[k]) + recv;
        }
    }
    float av = acc[0];
    av += __shfl_xor(av, 8);
    av += __shfl_xor(av, 16);
    av += __shfl_xor(av, 32);
    // lane l holds cross_total[bitrev3(l & 7)]

    // --- ent: full 6-round butterfly ---
#pragma unroll
    for (int d = 1; d < 64; d <<= 1) eacc += __shfl_xor(eacc, d);

    // --- combine the 4 waves via LDS, store 9 partials ---
    if (lane < 8)
        red[wave][((lane & 1) << 2) | (lane & 2) | ((lane & 4) >> 2)] = av;
    if (lane == 0)
        red[wave][8] = eacc;
    __syncthreads();

    if (tid < 9)
        part[(size_t)p * 9 + tid] = red[0][tid] + red[1][tid] + red[2][tid] + red[3][tid];
}

// ---------- phase 2: C build (4-span sum) + DP + permuted copy (512 blocks) ----------
__global__ __launch_bounds__(256) void permute_kernel(const float* __restrict__ pred,
                                                      const float* __restrict__ part,
                                                      float* __restrict__ out)
{
    __shared__ float C[64];     // C[i*8+j] = ent[j] - cross[i][j] (unscaled)
    __shared__ float dp[256];
    __shared__ int   choice[256];
    __shared__ int   inv8[8];   // col -> src row

    const int p    = blockIdx.x;   // pair = b*8 + jcol
    const int b    = p >> 3;
    const int tid  = threadIdx.x;

    if (tid < 64) {
        const int ii = tid >> 3, jj = tid & 7;
        float cross = 0.f, entj = 0.f;
#pragma unroll
        for (int s4 = 0; s4 < 4; ++s4) {
            cross += part[((size_t)((ii << 8) + (s4 << 6) + b)) * 9 + jj];
            entj  += part[((size_t)((jj << 8) + (s4 << 6) + b)) * 9 + 8];
        }
        C[tid] = entj - cross;
    }
    if (tid == 0) dp[0] = 0.f;
    __syncthreads();

    // --- Held-Karp DP over 255 masks, level-ordered; 32 mask slots per pass ---
    const int grp = tid >> 3;
    const int j   = tid & 7;
    for (int lvl = 1; lvl <= 8; ++lvl) {
        const int start = kTab.off[lvl - 1];
        const int end   = kTab.off[lvl];
        const float* Crow = &C[(lvl - 1) * 8];
        for (int bse = start; bse < end; bse += 32) {
            const int mi = bse + grp;
            if (mi < end) {
                const int M = kTab.masks[mi];
                float v  = 1e30f;
                int   bj = 0;
                if (M & (1 << j)) {
                    v  = dp[M ^ (1 << j)] + Crow[j];
                    bj = j;
                }
#pragma unroll
                for (int d = 1; d < 8; d <<= 1) {
                    const float ov = __shfl_xor(v, d);
                    const int   oj = __shfl_xor(bj, d);
                    if (ov < v) { v = ov; bj = oj; }
                }
                if (j == 0) { dp[M] = v; choice[M] = bj; }
            }
        }
        __syncthreads();
    }

    if (tid == 0) {
        int mask = 255;
        for (int r = 7; r >= 0; --r) {
            const int jj = choice[mask];
            inv8[jj] = r;              // column jj takes pred row r
            mask ^= 1 << jj;
        }
        if ((p & 7) == 0)              // one designated block per batch
            atomicAdd(out, dp[255] * (1.0f / (16384.0f * 512.0f)));
    }
    __syncthreads();

    // --- permuted copy of the full row (16384 elements = 4096 quads) ---
    const int src_row = inv8[p & 7];   // uniform per block
    const float* src  = pred + ((size_t)(b << 3) + src_row) * HW;
    float*      drow  = out + 1 + (size_t)p * HW;

#pragma unroll
    for (int m = 0; m < 16; ++m) {
        const int f = tid + 256 * m;              // quad index in [0,4096)
        const int e = 3 + 4 * f;
        if (f < 4095) {
            float4 v;
            v.x = src[e]; v.y = src[e + 1]; v.z = src[e + 2]; v.w = src[e + 3];
            *(float4*)(drow + e) = v;             // 16B-aligned
        } else {                                  // f==4095: head 3 + tail 1
            drow[0] = src[0]; drow[1] = src[1]; drow[2] = src[2];
            drow[16383] = src[16383];
        }
    }
}

extern "C" void kernel_launch(void* const* d_in, const int* in_sizes, int n_in,
                              void* d_out, int out_size, void* d_ws, size_t ws_size,
                              hipStream_t stream) {
    const float* pred = (const float*)d_in[0];
    const float* aug  = (const float*)d_in[1];
    float* out  = (float*)d_out;
    float* part = (float*)d_ws;                      // 2048*9 floats

    cost_kernel<<<dim3(2048), dim3(256), 0, stream>>>(pred, aug, part, out);
    permute_kernel<<<dim3(512), dim3(256), 0, stream>>>(pred, part, out);
}

// Round 11
// 164.568 us; speedup vs baseline: 1.4277x; 1.4277x over previous
//
#include <hip/hip_runtime.h>

// B=64, K=8, H=W=128 (HW=16384). float32 in/out.
// out[0] = loss scalar; out[1..] = pred_perm (B,K,H,W) flat.
//
// 2-dispatch pipeline. Session constraint set (r7-r10 counters):
//   (a) >=50% occupancy  (r8/r2: <=25% occ -> latency-bound ~40us)
//   (b) ZERO cross-block redundancy (r10: 8x aug re-reads vs dirty L3 ->
//       233MB fetch + 221MB forced evictions, 129us)
//   (c) low VGPR, no spill (r7: merged DP -> spill -> 86us)
//
//   cost_kernel : 2048 blocks (s5 = p>>6: x-span, b = p&63) x 256 thr
//                 = 8 blocks/CU x 4 waves = 32 waves/CU. I-SPLIT ACROSS WAVES:
//                 wave w computes pred rows {2w,2w+1} x all 8 aug (acc[16],
//                 ~50 VGPR, launch_bounds(256,8)). All 4 waves read the SAME
//                 aug window near-simultaneously -> within-block L1/L2 hits;
//                 unique HBM traffic = 67MB exactly. Epilogue: verified
//                 reduce-scatter at V=16 (4 rounds + 2 butterflies) + V=2 ent;
//                 waves own distinct rows -> LDS scatter, no sums.
//   permute_kernel: r0-verified: 72-wide span reduce (SPANS=32), Held-Karp DP
//                 (redundant per block), float4 permuted row copy, one block
//                 per batch atomicAdds the loss.

#define BB 64
#define KK 8
#define HW 16384
#define SPANS 32     // x-spans per batch (512 floats each)
#define EPSF 1e-15f

// ---------- compile-time mask table: all 255 nonzero 8-bit masks, level-ordered by popcount ----------
struct MaskTab {
    unsigned char masks[255];
    int off[9];
};

constexpr MaskTab make_tab() {
    MaskTab t{};
    int idx = 0;
    for (int p = 1; p <= 8; ++p) {
        t.off[p - 1] = idx;
        for (int m = 1; m < 256; ++m) {
            int c = 0;
            for (int b = 0; b < 8; ++b) c += (m >> b) & 1;
            if (c == p) t.masks[idx++] = (unsigned char)m;
        }
    }
    t.off[8] = idx;
    return t;
}

__constant__ MaskTab kTab = make_tab();

__device__ __forceinline__ float dot4(float4 t, float4 l) {
    return t.x * l.x + t.y * l.y + t.z * l.z + t.w * l.w;
}

__device__ __forceinline__ float4 log4(float4 a) {
    float4 r;
    r.x = __logf(a.x + EPSF); r.y = __logf(a.y + EPSF);
    r.z = __logf(a.z + EPSF); r.w = __logf(a.w + EPSF);
    return r;
}

// ---------- phase 1: wave-i-split cost partials, zero redundancy, full occupancy ----------
// Block p = s5*... : s5 = p>>6 (x-span 0..31), b = p&63. Wave w, lane l covers
// float offsets s5*512 + w2*256 + l*4 (w2=0,1). part[p][72] as in r0.
__global__ __launch_bounds__(256, 8) void cost_kernel(const float* __restrict__ pred,
                                                      const float* __restrict__ aug,
                                                      float* __restrict__ part,   // [2048][72]
                                                      float* __restrict__ out)
{
    __shared__ float red[4][18];

    const int p    = blockIdx.x;
    const int s5   = p >> 6;         // x-span 0..31
    const int b    = p & 63;         // batch
    const int tid  = threadIdx.x;
    const int wave = tid >> 6;       // owns pred rows 2w, 2w+1
    const int lane = tid & 63;

    if (p == 0 && tid == 0) out[0] = 0.f;   // loss accumulator init (pre-atomics)

    const float* pr0 = pred + ((size_t)b * KK + 2 * wave) * HW;   // row 2w
    const float* pr1 = pr0 + HW;                                   // row 2w+1
    const float* ab  = aug + (size_t)b * KK * HW;

    float acc[16];
#pragma unroll
    for (int v = 0; v < 16; ++v) acc[v] = 0.f;
    float e2[2] = {0.f, 0.f};

#pragma unroll
    for (int w2 = 0; w2 < 2; ++w2) {
        const int e = s5 * 512 + w2 * 256 + lane * 4;

        const float4 l0 = log4(*(const float4*)(pr0 + e));
        const float4 l1 = log4(*(const float4*)(pr1 + e));

#pragma unroll
        for (int j = 0; j < 8; ++j) {
            const float4 a = *(const float4*)(ab + (size_t)j * HW + e);
            acc[j]     += dot4(a, l0);
            acc[8 + j] += dot4(a, l1);
            if (j == 2 * wave)     e2[0] += dot4(a, log4(a));   // wave-uniform branch
            if (j == 2 * wave + 1) e2[1] += dot4(a, log4(a));
        }
    }

    // --- 4-round reduce-scatter over acc[16] + 2 butterflies (r2-verified pattern) ---
    // After 4 rounds lane l holds (16-lane-group partial of) acc[bitrev4(l&15)];
    // xor-16/32 butterflies finish the lane reduction.
#pragma unroll
    for (int r = 0; r < 4; ++r) {
        const int d    = 1 << r;
        const int half = 8 >> r;
        const bool hi  = (lane & d) != 0;
#pragma unroll
        for (int k = 0; k < half; ++k) {
            const float send = hi ? acc[k] : acc[k + half];
            const float recv = __shfl_xor(send, d);
            acc[k] = (hi ? acc[k + half] : acc[k]) + recv;
        }
    }
    float av = acc[0];
    av += __shfl_xor(av, 16);
    av += __shfl_xor(av, 32);
    // lane l holds total of acc[bitrev4(l&15)]  (v = il*8+j; il=v>>3, j=v&7)

    // --- ent: 1-round reduce-scatter over e2[2] + 5 butterflies ---
    {
        const bool hi = (lane & 1) != 0;
        const float send = hi ? e2[0] : e2[1];
        const float recv = __shfl_xor(send, 1);
        e2[0] = (hi ? e2[1] : e2[0]) + recv;
    }
    float ev = e2[0];
    ev += __shfl_xor(ev, 2);
    ev += __shfl_xor(ev, 4);
    ev += __shfl_xor(ev, 8);
    ev += __shfl_xor(ev, 16);
    ev += __shfl_xor(ev, 32);
    // lane l holds ent_total[2*wave + (l&1)]

    // --- LDS scatter (each wave owns distinct rows -> no sums) ---
    if (lane < 16) {
        const int v = ((lane & 1) << 3) | ((lane & 2) << 1) | ((lane & 4) >> 1) | ((lane & 8) >> 3);
        red[wave][v] = av;           // red[w][il*8+j] = cross[2w+il][j]
    }
    if (lane < 2)
        red[wave][16 + lane] = ev;   // red[w][16+il] = ent[2w+il]
    __syncthreads();

    if (tid < 64) {
        const int i = tid >> 3, j = tid & 7;
        part[(size_t)p * 72 + tid] = red[i >> 1][((i & 1) << 3) | j];
    } else if (tid < 72) {
        const int j = tid - 64;
        part[(size_t)p * 72 + tid] = red[j >> 1][16 + (j & 1)];
    }
}

// ---------- phase 2: span reduce + DP + permuted copy (512 blocks, r0-verified) ----------
__global__ __launch_bounds__(256) void permute_kernel(const float* __restrict__ pred,
                                                      const float* __restrict__ part,
                                                      float* __restrict__ out)
{
    __shared__ float red[72];
    __shared__ float C[64];     // C[i*8+j] = ent[j] - cross[i][j] (unscaled)
    __shared__ float dp[256];
    __shared__ int   choice[256];
    __shared__ int   inv8[8];   // col -> src row

    const int p    = blockIdx.x;   // pair = b*8 + jcol
    const int b    = p >> 3;
    const int tid  = threadIdx.x;

    // --- reduce the 32 span-partials for batch b ---
    if (tid < 72) {
        float s = 0.f;
#pragma unroll
        for (int s5 = 0; s5 < SPANS; ++s5)
            s += part[(size_t)((s5 << 6) + b) * 72 + tid];
        red[tid] = s;
    }
    if (tid == 0) dp[0] = 0.f;
    __syncthreads();
    if (tid < 64) C[tid] = red[64 + (tid & 7)] - red[tid];
    __syncthreads();

    // --- Held-Karp DP over 255 masks, level-ordered; 32 mask slots per pass ---
    const int grp = tid >> 3;
    const int j   = tid & 7;
    for (int lvl = 1; lvl <= 8; ++lvl) {
        const int start = kTab.off[lvl - 1];
        const int end   = kTab.off[lvl];
        const float* Crow = &C[(lvl - 1) * 8];
        for (int bse = start; bse < end; bse += 32) {
            const int mi = bse + grp;
            if (mi < end) {
                const int M = kTab.masks[mi];
                float v  = 1e30f;
                int   bj = 0;
                if (M & (1 << j)) {
                    v  = dp[M ^ (1 << j)] + Crow[j];
                    bj = j;
                }
#pragma unroll
                for (int d = 1; d < 8; d <<= 1) {
                    const float ov = __shfl_xor(v, d);
                    const int   oj = __shfl_xor(bj, d);
                    if (ov < v) { v = ov; bj = oj; }
                }
                if (j == 0) { dp[M] = v; choice[M] = bj; }
            }
        }
        __syncthreads();
    }

    if (tid == 0) {
        int mask = 255;
        for (int r = 7; r >= 0; --r) {
            const int jj = choice[mask];
            inv8[jj] = r;              // column jj takes pred row r
            mask ^= 1 << jj;
        }
        if ((p & 7) == 0)              // one designated block per batch
            atomicAdd(out, dp[255] * (1.0f / (16384.0f * 512.0f)));
    }
    __syncthreads();

    // --- permuted copy of the full row (16384 elements = 4096 quads) ---
    const int src_row = inv8[p & 7];   // uniform per block
    const float* src  = pred + ((size_t)(b << 3) + src_row) * HW;
    float*      drow  = out + 1 + (size_t)p * HW;

#pragma unroll
    for (int m = 0; m < 16; ++m) {
        const int f = tid + 256 * m;              // quad index in [0,4096)
        const int e = 3 + 4 * f;
        if (f < 4095) {
            float4 v;
            v.x = src[e]; v.y = src[e + 1]; v.z = src[e + 2]; v.w = src[e + 3];
            *(float4*)(drow + e) = v;             // 16B-aligned
        } else {                                  // f==4095: head 3 + tail 1
            drow[0] = src[0]; drow[1] = src[1]; drow[2] = src[2];
            drow[16383] = src[16383];
        }
    }
}

extern "C" void kernel_launch(void* const* d_in, const int* in_sizes, int n_in,
                              void* d_out, int out_size, void* d_ws, size_t ws_size,
                              hipStream_t stream) {
    const float* pred = (const float*)d_in[0];
    const float* aug  = (const float*)d_in[1];
    float* out  = (float*)d_out;
    float* part = (float*)d_ws;                      // 2048*72 floats

    cost_kernel<<<dim3(2048), dim3(256), 0, stream>>>(pred, aug, part, out);
    permute_kernel<<<dim3(512), dim3(256), 0, stream>>>(pred, part, out);
}